// Round 1
// baseline (111.759 us; speedup 1.0000x reference)
//
#include <hip/hip_runtime.h>
#include <math.h>

#define BB 64
#define TT 2048
#define EH 512   // ENC_H
#define DH 512   // DEC_H
#define PP 256   // P
#define NC 32            // chunks per batch row
#define TC (TT / NC)     // 64 t-rows per chunk
#define ROWS_PER_WAVE (TC / 4)   // 16

// ---------------------------------------------------------------------------
// Kernel 1: per-b   q = dec@Wq + bq ;  qk = Wk @ q ;  c0 = bk . q
// ---------------------------------------------------------------------------
__global__ __launch_bounds__(256) void attn_prep(
    const float* __restrict__ dec,   // [B, DH]
    const float* __restrict__ Wk,    // [EH, PP]
    const float* __restrict__ bk,    // [PP]
    const float* __restrict__ Wq,    // [DH, PP]
    const float* __restrict__ bq,    // [PP]
    float* __restrict__ qk,          // [B, EH]
    float* __restrict__ c0)          // [B]
{
    const int b   = blockIdx.x;
    const int tid = threadIdx.x;
    __shared__ float s_dec[DH];
    __shared__ float s_q[PP];
    __shared__ float s_red[256];

    for (int e = tid; e < DH; e += 256) s_dec[e] = dec[b * DH + e];
    __syncthreads();

    // query[p] for p = tid  (coalesced Wq column walk)
    float acc = bq[tid];
    #pragma unroll 8
    for (int e = 0; e < DH; ++e)
        acc = fmaf(s_dec[e], Wq[e * PP + tid], acc);
    s_q[tid] = acc;

    // c0 = dot(bk, q)
    s_red[tid] = acc * bk[tid];
    __syncthreads();
    for (int off = 128; off > 0; off >>= 1) {
        if (tid < off) s_red[tid] += s_red[tid + off];
        __syncthreads();
    }
    if (tid == 0) c0[b] = s_red[0];

    // qk[e] = sum_p Wk[e,p] * q[p]
    for (int e = tid; e < EH; e += 256) {
        float a = 0.f;
        #pragma unroll 8
        for (int p = 0; p < PP; ++p)
            a = fmaf(Wk[e * PP + p], s_q[p], a);
        qk[b * EH + e] = a;
    }
}

// ---------------------------------------------------------------------------
// Kernel 2: streaming pass over enc with online softmax.
// grid = B*NC blocks, 256 threads (4 waves). Wave w handles rows t0+w, +4, ...
// Lane l holds enc elements e in [4l,4l+4) and [256+4l, 256+4l+4).
// ---------------------------------------------------------------------------
__global__ __launch_bounds__(256) void attn_main(
    const float* __restrict__ enc,   // [B, T, EH]
    const float* __restrict__ qk,    // [B, EH]
    const float* __restrict__ c0,    // [B]
    float* __restrict__ raw,         // [B, T]  (attn region of d_out)
    float* __restrict__ mc,          // [B, NC]
    float* __restrict__ lc,          // [B, NC]
    float* __restrict__ ctxc)        // [B, NC, EH]
{
    const int blk  = blockIdx.x;
    const int b    = blk / NC;
    const int c    = blk % NC;
    const int tid  = threadIdx.x;
    const int wave = tid >> 6;
    const int lane = tid & 63;
    const int e0   = lane * 4;

    const float* encb = enc + (size_t)b * TT * EH;

    const float4 qk0 = *(const float4*)(qk + b * EH + e0);
    const float4 qk1 = *(const float4*)(qk + b * EH + 256 + e0);
    const float  cc  = c0[b];

    float  m = -1e30f, l = 0.f;
    float4 ctx0 = {0.f, 0.f, 0.f, 0.f};
    float4 ctx1 = {0.f, 0.f, 0.f, 0.f};

    const int tbase = c * TC + wave;          // rows: tbase + 4*it

    const float* row0 = encb + (size_t)tbase * EH;
    float4 a0 = *(const float4*)(row0 + e0);
    float4 a1 = *(const float4*)(row0 + 256 + e0);

    for (int it = 0; it < ROWS_PER_WAVE; ++it) {
        // prefetch next row (clamped; last iter re-reads L1-hot row)
        const int itn = (it + 1 < ROWS_PER_WAVE) ? it + 1 : ROWS_PER_WAVE - 1;
        const float* nrow = encb + (size_t)(tbase + 4 * itn) * EH;
        float4 n0 = *(const float4*)(nrow + e0);
        float4 n1 = *(const float4*)(nrow + 256 + e0);

        // score = enc_row . qk + c0
        float d = a0.x * qk0.x + a0.y * qk0.y + a0.z * qk0.z + a0.w * qk0.w
                + a1.x * qk1.x + a1.y * qk1.y + a1.z * qk1.z + a1.w * qk1.w;
        #pragma unroll
        for (int off = 32; off > 0; off >>= 1)
            d += __shfl_xor(d, off, 64);
        const float s = d + cc;

        const int t = tbase + 4 * it;
        if (lane == 0) raw[(size_t)b * TT + t] = s;

        // online softmax update
        const float mn    = fmaxf(m, s);
        const float scale = __expf(m - mn);
        const float p     = __expf(s - mn);
        l = l * scale + p;
        ctx0.x = ctx0.x * scale + p * a0.x;
        ctx0.y = ctx0.y * scale + p * a0.y;
        ctx0.z = ctx0.z * scale + p * a0.z;
        ctx0.w = ctx0.w * scale + p * a0.w;
        ctx1.x = ctx1.x * scale + p * a1.x;
        ctx1.y = ctx1.y * scale + p * a1.y;
        ctx1.z = ctx1.z * scale + p * a1.z;
        ctx1.w = ctx1.w * scale + p * a1.w;
        m = mn;

        a0 = n0; a1 = n1;
    }

    // merge the 4 waves of this block
    __shared__ float s_m[4], s_l[4];
    __shared__ float s_ctx[4][EH];
    *(float4*)&s_ctx[wave][e0]       = ctx0;
    *(float4*)&s_ctx[wave][256 + e0] = ctx1;
    if (lane == 0) { s_m[wave] = m; s_l[wave] = l; }
    __syncthreads();

    const float mb = fmaxf(fmaxf(s_m[0], s_m[1]), fmaxf(s_m[2], s_m[3]));
    const float w0 = __expf(s_m[0] - mb);
    const float w1 = __expf(s_m[1] - mb);
    const float w2 = __expf(s_m[2] - mb);
    const float w3 = __expf(s_m[3] - mb);

    if (tid == 0) {
        mc[b * NC + c] = mb;
        lc[b * NC + c] = s_l[0] * w0 + s_l[1] * w1 + s_l[2] * w2 + s_l[3] * w3;
    }
    float* cdst = ctxc + ((size_t)b * NC + c) * EH;
    for (int e = tid; e < EH; e += 256)
        cdst[e] = s_ctx[0][e] * w0 + s_ctx[1][e] * w1
                + s_ctx[2][e] * w2 + s_ctx[3][e] * w3;
}

// ---------------------------------------------------------------------------
// Kernel 3: per-b combine of chunk partials; context = (ctx/l)@Wv + bv;
//           attn[b,t] = exp(raw - m) / l   (in place in d_out)
// ---------------------------------------------------------------------------
__global__ __launch_bounds__(256) void attn_combine(
    const float* __restrict__ mc,    // [B, NC]
    const float* __restrict__ lc,    // [B, NC]
    const float* __restrict__ ctxc,  // [B, NC, EH]
    const float* __restrict__ Wv,    // [EH, PP]
    const float* __restrict__ bv,    // [PP]
    float* __restrict__ out_ctx,     // [B, PP]
    float* __restrict__ attn)        // [B, T] (holds raw on entry)
{
    const int b   = blockIdx.x;
    const int tid = threadIdx.x;

    float m = -1e30f;
    for (int i = 0; i < NC; ++i) m = fmaxf(m, mc[b * NC + i]);
    float l = 0.f;
    for (int i = 0; i < NC; ++i) l += lc[b * NC + i] * __expf(mc[b * NC + i] - m);
    const float inv_l = 1.0f / l;

    __shared__ float s_w[NC];
    if (tid < NC) s_w[tid] = __expf(mc[b * NC + tid] - m);
    __syncthreads();

    __shared__ float s_ctx[EH];
    for (int e = tid; e < EH; e += 256) {
        float acc = 0.f;
        #pragma unroll 8
        for (int i = 0; i < NC; ++i)
            acc += ctxc[((size_t)b * NC + i) * EH + e] * s_w[i];
        s_ctx[e] = acc * inv_l;
    }
    __syncthreads();

    // context[p] = bv[p] + sum_e s_ctx[e] * Wv[e,p]
    float acc = bv[tid];
    #pragma unroll 8
    for (int e = 0; e < EH; ++e)
        acc = fmaf(s_ctx[e], Wv[e * PP + tid], acc);
    out_ctx[b * PP + tid] = acc;

    // attn rewrite in place
    for (int t = tid; t < TT; t += 256) {
        const float r = attn[(size_t)b * TT + t];
        attn[(size_t)b * TT + t] = __expf(r - m) * inv_l;
    }
}

// ---------------------------------------------------------------------------
extern "C" void kernel_launch(void* const* d_in, const int* in_sizes, int n_in,
                              void* d_out, int out_size, void* d_ws, size_t ws_size,
                              hipStream_t stream) {
    const float* dec = (const float*)d_in[0];
    const float* enc = (const float*)d_in[1];
    // d_in[2] = encoder_lens: UNUSED by the reference computation
    const float* Wk  = (const float*)d_in[3];
    const float* bk  = (const float*)d_in[4];
    const float* Wv  = (const float*)d_in[5];
    const float* bv  = (const float*)d_in[6];
    const float* Wq  = (const float*)d_in[7];
    const float* bq  = (const float*)d_in[8];

    float* out_ctx = (float*)d_out;              // [B, PP]
    float* attn    = out_ctx + BB * PP;          // [B, T]

    float* qk   = (float*)d_ws;                  // B*EH
    float* c0   = qk + BB * EH;                  // B
    float* mc   = c0 + BB;                       // B*NC
    float* lc   = mc + BB * NC;                  // B*NC
    float* ctxc = lc + BB * NC;                  // B*NC*EH

    attn_prep<<<BB, 256, 0, stream>>>(dec, Wk, bk, Wq, bq, qk, c0);
    attn_main<<<BB * NC, 256, 0, stream>>>(enc, qk, c0, attn, mc, lc, ctxc);
    attn_combine<<<BB, 256, 0, stream>>>(mc, lc, ctxc, Wv, bv, out_ctx, attn);
}

// Round 2
// 72.329 us; speedup vs baseline: 1.5452x; 1.5452x over previous
//
#include <hip/hip_runtime.h>
#include <math.h>

#define BB 64
#define TT 2048
#define EH 512   // ENC_H
#define DH 512   // DEC_H
#define PP 256   // P
#define NC 32            // chunks per batch row
#define TC (TT / NC)     // 64 t-rows per chunk
#define ROWS_PER_WAVE (TC / 4)   // 16

// ---------------------------------------------------------------------------
// K1: q[b,p] = dec[b,:] . Wq[:,p] + bq[p]
// grid = B*4 (p-quarters), 256 thr: p = (tid&63)+64*pq, d-chunk = tid>>6.
// Wq reads coalesced (64 consecutive p per wave); dec[d] is a wave broadcast.
// ---------------------------------------------------------------------------
__global__ __launch_bounds__(256) void k_qproj(
    const float* __restrict__ dec, const float* __restrict__ Wq,
    const float* __restrict__ bq, float* __restrict__ q)
{
    const int b  = blockIdx.x >> 2;
    const int pq = blockIdx.x & 3;
    const int tid = threadIdx.x;
    const int p  = pq * 64 + (tid & 63);
    const int dc = tid >> 6;

    float acc = 0.f;
    const float* decb = dec + b * DH;
    #pragma unroll 8
    for (int d = dc * 128; d < dc * 128 + 128; ++d)
        acc = fmaf(decb[d], Wq[d * PP + p], acc);

    __shared__ float s_red[256];
    s_red[tid] = acc;
    __syncthreads();
    if (tid < 64) {
        float r = s_red[tid] + s_red[tid + 64] + s_red[tid + 128] + s_red[tid + 192];
        q[b * PP + p] = r + bq[p];
    }
}

// ---------------------------------------------------------------------------
// K2: qk[b,e] = Wk[e,:] . q[b,:]
// grid = B*32 (16 e's per block), 256 thr = 16 groups of 16 lanes; each group
// owns one e-row: lane reads 4 float4 (coalesced 256B/group), 4-step shfl.
// ---------------------------------------------------------------------------
__global__ __launch_bounds__(256) void k_kfold(
    const float* __restrict__ Wk, const float* __restrict__ q,
    float* __restrict__ qk)
{
    const int b   = blockIdx.x >> 5;
    const int et  = blockIdx.x & 31;
    const int grp = threadIdx.x >> 4;
    const int l16 = threadIdx.x & 15;
    const int e   = et * 16 + grp;

    const float* wrow = Wk + e * PP;
    const float* qb   = q + b * PP;

    float acc = 0.f;
    #pragma unroll
    for (int k = 0; k < 4; ++k) {
        const float4 w  = *(const float4*)(wrow + l16 * 4 + k * 64);
        const float4 qv = *(const float4*)(qb   + l16 * 4 + k * 64);
        acc += w.x * qv.x + w.y * qv.y + w.z * qv.z + w.w * qv.w;
    }
    #pragma unroll
    for (int off = 1; off < 16; off <<= 1)
        acc += __shfl_xor(acc, off, 64);
    if (l16 == 0) qk[b * EH + e] = acc;
}

// ---------------------------------------------------------------------------
// K3: streaming pass over enc with online softmax (c0 dropped: softmax is
// shift-invariant, and raw is only ever used post-softmax).
// grid = B*NC blocks, 256 threads (4 waves).
// ---------------------------------------------------------------------------
__global__ __launch_bounds__(256) void attn_main(
    const float* __restrict__ enc,   // [B, T, EH]
    const float* __restrict__ qk,    // [B, EH]
    float* __restrict__ raw,         // [B, T]  (attn region of d_out)
    float* __restrict__ mc,          // [B, NC]
    float* __restrict__ lc,          // [B, NC]
    float* __restrict__ ctxc)        // [B, NC, EH]
{
    const int blk  = blockIdx.x;
    const int b    = blk / NC;
    const int c    = blk % NC;
    const int tid  = threadIdx.x;
    const int wave = tid >> 6;
    const int lane = tid & 63;
    const int e0   = lane * 4;

    const float* encb = enc + (size_t)b * TT * EH;

    const float4 qk0 = *(const float4*)(qk + b * EH + e0);
    const float4 qk1 = *(const float4*)(qk + b * EH + 256 + e0);

    float  m = -1e30f, l = 0.f;
    float4 ctx0 = {0.f, 0.f, 0.f, 0.f};
    float4 ctx1 = {0.f, 0.f, 0.f, 0.f};

    const int tbase = c * TC + wave;          // rows: tbase + 4*it

    const float* row0 = encb + (size_t)tbase * EH;
    float4 a0 = *(const float4*)(row0 + e0);
    float4 a1 = *(const float4*)(row0 + 256 + e0);

    for (int it = 0; it < ROWS_PER_WAVE; ++it) {
        const int itn = (it + 1 < ROWS_PER_WAVE) ? it + 1 : ROWS_PER_WAVE - 1;
        const float* nrow = encb + (size_t)(tbase + 4 * itn) * EH;
        float4 n0 = *(const float4*)(nrow + e0);
        float4 n1 = *(const float4*)(nrow + 256 + e0);

        float d = a0.x * qk0.x + a0.y * qk0.y + a0.z * qk0.z + a0.w * qk0.w
                + a1.x * qk1.x + a1.y * qk1.y + a1.z * qk1.z + a1.w * qk1.w;
        #pragma unroll
        for (int off = 32; off > 0; off >>= 1)
            d += __shfl_xor(d, off, 64);
        const float s = d;

        const int t = tbase + 4 * it;
        if (lane == 0) raw[(size_t)b * TT + t] = s;

        const float mn    = fmaxf(m, s);
        const float scale = __expf(m - mn);
        const float p     = __expf(s - mn);
        l = l * scale + p;
        ctx0.x = ctx0.x * scale + p * a0.x;
        ctx0.y = ctx0.y * scale + p * a0.y;
        ctx0.z = ctx0.z * scale + p * a0.z;
        ctx0.w = ctx0.w * scale + p * a0.w;
        ctx1.x = ctx1.x * scale + p * a1.x;
        ctx1.y = ctx1.y * scale + p * a1.y;
        ctx1.z = ctx1.z * scale + p * a1.z;
        ctx1.w = ctx1.w * scale + p * a1.w;
        m = mn;

        a0 = n0; a1 = n1;
    }

    __shared__ float s_m[4], s_l[4];
    __shared__ float s_ctx[4][EH];
    *(float4*)&s_ctx[wave][e0]       = ctx0;
    *(float4*)&s_ctx[wave][256 + e0] = ctx1;
    if (lane == 0) { s_m[wave] = m; s_l[wave] = l; }
    __syncthreads();

    const float mb = fmaxf(fmaxf(s_m[0], s_m[1]), fmaxf(s_m[2], s_m[3]));
    const float w0 = __expf(s_m[0] - mb);
    const float w1 = __expf(s_m[1] - mb);
    const float w2 = __expf(s_m[2] - mb);
    const float w3 = __expf(s_m[3] - mb);

    if (tid == 0) {
        mc[b * NC + c] = mb;
        lc[b * NC + c] = s_l[0] * w0 + s_l[1] * w1 + s_l[2] * w2 + s_l[3] * w3;
    }
    float* cdst = ctxc + ((size_t)b * NC + c) * EH;
    for (int e = tid; e < EH; e += 256)
        cdst[e] = s_ctx[0][e] * w0 + s_ctx[1][e] * w1
                + s_ctx[2][e] * w2 + s_ctx[3][e] * w3;
}

// ---------------------------------------------------------------------------
// K4: per (b, p-quarter) block: merge chunk partials (redundant, tiny),
// sctx in LDS, context = sctx @ Wv[:,p-quarter] + bv, rewrite attn quarter.
// grid = B*4 = 256 blocks (1/CU), 256 thr.
// ---------------------------------------------------------------------------
__global__ __launch_bounds__(256) void k_finish(
    const float* __restrict__ mc,    // [B, NC]
    const float* __restrict__ lc,    // [B, NC]
    const float* __restrict__ ctxc,  // [B, NC, EH]
    const float* __restrict__ Wv,    // [EH, PP]
    const float* __restrict__ bv,    // [PP]
    float* __restrict__ out_ctx,     // [B, PP]
    float* __restrict__ attn)        // [B, T] (holds raw on entry)
{
    const int b   = blockIdx.x >> 2;
    const int pq  = blockIdx.x & 3;
    const int tid = threadIdx.x;

    float m = -1e30f;
    #pragma unroll 8
    for (int i = 0; i < NC; ++i) m = fmaxf(m, mc[b * NC + i]);
    float l = 0.f;
    #pragma unroll 8
    for (int i = 0; i < NC; ++i) l += lc[b * NC + i] * __expf(mc[b * NC + i] - m);
    const float inv_l = 1.0f / l;

    __shared__ float s_w[NC];
    __shared__ float s_ctx[EH];
    if (tid < NC) s_w[tid] = __expf(mc[b * NC + tid] - m);
    __syncthreads();

    for (int e = tid; e < EH; e += 256) {
        float acc = 0.f;
        #pragma unroll 8
        for (int i = 0; i < NC; ++i)
            acc += ctxc[((size_t)b * NC + i) * EH + e] * s_w[i];
        s_ctx[e] = acc * inv_l;
    }
    __syncthreads();

    // context for this p-quarter: p = pq*64 + (tid&63), e-chunk = tid>>6
    const int p  = pq * 64 + (tid & 63);
    const int dc = tid >> 6;
    float acc = 0.f;
    #pragma unroll 8
    for (int e = dc * 128; e < dc * 128 + 128; ++e)
        acc = fmaf(s_ctx[e], Wv[e * PP + p], acc);

    __shared__ float s_red[256];
    s_red[tid] = acc;
    __syncthreads();
    if (tid < 64)
        out_ctx[b * PP + p] = s_red[tid] + s_red[tid + 64]
                            + s_red[tid + 128] + s_red[tid + 192] + bv[p];

    // attn rewrite for this quarter: t in [pq*512, pq*512+512)
    for (int i = tid; i < TT / 4; i += 256) {
        const int t = pq * (TT / 4) + i;
        const float r = attn[(size_t)b * TT + t];
        attn[(size_t)b * TT + t] = __expf(r - m) * inv_l;
    }
}

// ---------------------------------------------------------------------------
extern "C" void kernel_launch(void* const* d_in, const int* in_sizes, int n_in,
                              void* d_out, int out_size, void* d_ws, size_t ws_size,
                              hipStream_t stream) {
    const float* dec = (const float*)d_in[0];
    const float* enc = (const float*)d_in[1];
    // d_in[2] = encoder_lens: unused by the reference computation
    const float* Wk  = (const float*)d_in[3];
    // d_in[4] = bk: drops out (softmax shift invariance)
    const float* Wv  = (const float*)d_in[5];
    const float* bv  = (const float*)d_in[6];
    const float* Wq  = (const float*)d_in[7];
    const float* bq  = (const float*)d_in[8];

    float* out_ctx = (float*)d_out;              // [B, PP]
    float* attn    = out_ctx + BB * PP;          // [B, T]

    float* q    = (float*)d_ws;                  // B*PP
    float* qk   = q + BB * PP;                   // B*EH
    float* mc   = qk + BB * EH;                  // B*NC
    float* lc   = mc + BB * NC;                  // B*NC
    float* ctxc = lc + BB * NC;                  // B*NC*EH

    k_qproj<<<BB * 4, 256, 0, stream>>>(dec, Wq, bq, q);
    k_kfold<<<BB * 32, 256, 0, stream>>>(Wk, q, qk);
    attn_main<<<BB * NC, 256, 0, stream>>>(enc, qk, attn, mc, lc, ctxc);
    k_finish<<<BB * 4, 256, 0, stream>>>(mc, lc, ctxc, Wv, bv, out_ctx, attn);
}

// Round 4
// 65.198 us; speedup vs baseline: 1.7141x; 1.1094x over previous
//
#include <hip/hip_runtime.h>
#include <math.h>

#define BB 64
#define TT 2048
#define EH 512   // ENC_H
#define DH 512   // DEC_H
#define PP 256   // P
#define NC 16            // chunks per batch row
#define TC (TT / NC)     // 128 t-rows per chunk
#define ROWS_PER_WAVE (TC / 4)   // 32

typedef float vfloat4 __attribute__((ext_vector_type(4)));

// ---------------------------------------------------------------------------
// K1: q[b,p] = dec[b,:] . Wq[:,p] + bq[p]
// grid = B*4 (p-quarters), 256 thr: p = (tid&63)+64*pq, d-chunk = tid>>6.
// ---------------------------------------------------------------------------
__global__ __launch_bounds__(256) void k_qproj(
    const float* __restrict__ dec, const float* __restrict__ Wq,
    const float* __restrict__ bq, float* __restrict__ q)
{
    const int b  = blockIdx.x >> 2;
    const int pq = blockIdx.x & 3;
    const int tid = threadIdx.x;
    const int p  = pq * 64 + (tid & 63);
    const int dc = tid >> 6;

    float acc = 0.f;
    const float* decb = dec + b * DH;
    #pragma unroll 8
    for (int d = dc * 128; d < dc * 128 + 128; ++d)
        acc = fmaf(decb[d], Wq[d * PP + p], acc);

    __shared__ float s_red[256];
    s_red[tid] = acc;
    __syncthreads();
    if (tid < 64) {
        float r = s_red[tid] + s_red[tid + 64] + s_red[tid + 128] + s_red[tid + 192];
        q[b * PP + p] = r + bq[p];
    }
}

// ---------------------------------------------------------------------------
// K2: qk[b,e] = Wk[e,:] . q[b,:]
// grid = B*32 (16 e's per block), 256 thr = 16 groups of 16 lanes.
// ---------------------------------------------------------------------------
__global__ __launch_bounds__(256) void k_kfold(
    const float* __restrict__ Wk, const float* __restrict__ q,
    float* __restrict__ qk)
{
    const int b   = blockIdx.x >> 5;
    const int et  = blockIdx.x & 31;
    const int grp = threadIdx.x >> 4;
    const int l16 = threadIdx.x & 15;
    const int e   = et * 16 + grp;

    const float* wrow = Wk + e * PP;
    const float* qb   = q + b * PP;

    float acc = 0.f;
    #pragma unroll
    for (int k = 0; k < 4; ++k) {
        const float4 w  = *(const float4*)(wrow + l16 * 4 + k * 64);
        const float4 qv = *(const float4*)(qb   + l16 * 4 + k * 64);
        acc += w.x * qv.x + w.y * qv.y + w.z * qv.z + w.w * qv.w;
    }
    #pragma unroll
    for (int off = 1; off < 16; off <<= 1)
        acc += __shfl_xor(acc, off, 64);
    if (l16 == 0) qk[b * EH + e] = acc;
}

// ---------------------------------------------------------------------------
// K3: streaming pass over enc with online softmax.
// grid = B*NC = 1024 blocks, 256 thr (4 waves), 32 rows/wave.
// ---------------------------------------------------------------------------
__global__ __launch_bounds__(256) void attn_main(
    const float* __restrict__ enc,   // [B, T, EH]
    const float* __restrict__ qk,    // [B, EH]
    float* __restrict__ raw,         // [B, T]  (attn region of d_out)
    float* __restrict__ mc,          // [B, NC]
    float* __restrict__ lc,          // [B, NC]
    float* __restrict__ ctxc)        // [B, NC, EH]
{
    const int blk  = blockIdx.x;
    const int b    = blk / NC;
    const int c    = blk % NC;
    const int tid  = threadIdx.x;
    const int wave = tid >> 6;
    const int lane = tid & 63;
    const int e0   = lane * 4;

    const float* encb = enc + (size_t)b * TT * EH;

    const float4 qk0 = *(const float4*)(qk + b * EH + e0);
    const float4 qk1 = *(const float4*)(qk + b * EH + 256 + e0);

    float  m = -1e30f, l = 0.f;
    float4 ctx0 = {0.f, 0.f, 0.f, 0.f};
    float4 ctx1 = {0.f, 0.f, 0.f, 0.f};

    const int tbase = c * TC + wave;          // rows: tbase + 4*it

    const vfloat4* row0 = (const vfloat4*)(encb + (size_t)tbase * EH);
    vfloat4 a0 = __builtin_nontemporal_load(row0 + lane);
    vfloat4 a1 = __builtin_nontemporal_load(row0 + 64 + lane);

    for (int it = 0; it < ROWS_PER_WAVE; ++it) {
        // prefetch next row (last iter: re-issue current row, L1-hot)
        const int itn = (it + 1 < ROWS_PER_WAVE) ? it + 1 : it;
        const vfloat4* nrow = (const vfloat4*)(encb + (size_t)(tbase + 4 * itn) * EH);
        vfloat4 n0 = __builtin_nontemporal_load(nrow + lane);
        vfloat4 n1 = __builtin_nontemporal_load(nrow + 64 + lane);

        float d = a0.x * qk0.x + a0.y * qk0.y + a0.z * qk0.z + a0.w * qk0.w
                + a1.x * qk1.x + a1.y * qk1.y + a1.z * qk1.z + a1.w * qk1.w;
        #pragma unroll
        for (int off = 32; off > 0; off >>= 1)
            d += __shfl_xor(d, off, 64);
        const float s = d;

        const int t = tbase + 4 * it;
        if (lane == 0) raw[(size_t)b * TT + t] = s;

        const float mn    = fmaxf(m, s);
        const float scale = __expf(m - mn);
        const float p     = __expf(s - mn);
        l = l * scale + p;
        ctx0.x = ctx0.x * scale + p * a0.x;
        ctx0.y = ctx0.y * scale + p * a0.y;
        ctx0.z = ctx0.z * scale + p * a0.z;
        ctx0.w = ctx0.w * scale + p * a0.w;
        ctx1.x = ctx1.x * scale + p * a1.x;
        ctx1.y = ctx1.y * scale + p * a1.y;
        ctx1.z = ctx1.z * scale + p * a1.z;
        ctx1.w = ctx1.w * scale + p * a1.w;
        m = mn;

        a0 = n0; a1 = n1;
    }

    // merge the 4 waves of this block
    __shared__ float s_m[4], s_l[4];
    __shared__ float s_ctx[4][EH];
    *(float4*)&s_ctx[wave][e0]       = ctx0;
    *(float4*)&s_ctx[wave][256 + e0] = ctx1;
    if (lane == 0) { s_m[wave] = m; s_l[wave] = l; }
    __syncthreads();

    const float mb = fmaxf(fmaxf(s_m[0], s_m[1]), fmaxf(s_m[2], s_m[3]));
    const float w0 = __expf(s_m[0] - mb);
    const float w1 = __expf(s_m[1] - mb);
    const float w2 = __expf(s_m[2] - mb);
    const float w3 = __expf(s_m[3] - mb);

    if (tid == 0) {
        mc[b * NC + c] = mb;
        lc[b * NC + c] = s_l[0] * w0 + s_l[1] * w1 + s_l[2] * w2 + s_l[3] * w3;
    }
    float* cdst = ctxc + ((size_t)b * NC + c) * EH;
    for (int e = tid; e < EH; e += 256)
        cdst[e] = s_ctx[0][e] * w0 + s_ctx[1][e] * w1
                + s_ctx[2][e] * w2 + s_ctx[3][e] * w3;
}

// ---------------------------------------------------------------------------
// K4: per (b, p-quarter): merge chunk partials, context = sctx@Wv + bv,
// rewrite attn quarter. grid = B*4 = 256 blocks.
// ---------------------------------------------------------------------------
__global__ __launch_bounds__(256) void k_finish(
    const float* __restrict__ mc,    // [B, NC]
    const float* __restrict__ lc,    // [B, NC]
    const float* __restrict__ ctxc,  // [B, NC, EH]
    const float* __restrict__ Wv,    // [EH, PP]
    const float* __restrict__ bv,    // [PP]
    float* __restrict__ out_ctx,     // [B, PP]
    float* __restrict__ attn)        // [B, T] (holds raw on entry)
{
    const int b   = blockIdx.x >> 2;
    const int pq  = blockIdx.x & 3;
    const int tid = threadIdx.x;

    float m = -1e30f;
    #pragma unroll
    for (int i = 0; i < NC; ++i) m = fmaxf(m, mc[b * NC + i]);
    float l = 0.f;
    #pragma unroll
    for (int i = 0; i < NC; ++i) l += lc[b * NC + i] * __expf(mc[b * NC + i] - m);
    const float inv_l = 1.0f / l;

    __shared__ float s_w[NC];
    __shared__ float s_ctx[EH];
    if (tid < NC) s_w[tid] = __expf(mc[b * NC + tid] - m);
    __syncthreads();

    for (int e = tid; e < EH; e += 256) {
        float acc = 0.f;
        #pragma unroll
        for (int i = 0; i < NC; ++i)
            acc += ctxc[((size_t)b * NC + i) * EH + e] * s_w[i];
        s_ctx[e] = acc * inv_l;
    }
    __syncthreads();

    // context for this p-quarter: p = pq*64 + (tid&63), e-chunk = tid>>6
    const int p  = pq * 64 + (tid & 63);
    const int dc = tid >> 6;
    float acc = 0.f;
    #pragma unroll 8
    for (int e = dc * 128; e < dc * 128 + 128; ++e)
        acc = fmaf(s_ctx[e], Wv[e * PP + p], acc);

    __shared__ float s_red[256];
    s_red[tid] = acc;
    __syncthreads();
    if (tid < 64)
        out_ctx[b * PP + p] = s_red[tid] + s_red[tid + 64]
                            + s_red[tid + 128] + s_red[tid + 192] + bv[p];

    // attn rewrite for this quarter
    #pragma unroll
    for (int i = 0; i < TT / 4 / 256; ++i) {
        const int t = pq * (TT / 4) + i * 256 + tid;
        const float r = attn[(size_t)b * TT + t];
        attn[(size_t)b * TT + t] = __expf(r - m) * inv_l;
    }
}

// ---------------------------------------------------------------------------
extern "C" void kernel_launch(void* const* d_in, const int* in_sizes, int n_in,
                              void* d_out, int out_size, void* d_ws, size_t ws_size,
                              hipStream_t stream) {
    const float* dec = (const float*)d_in[0];
    const float* enc = (const float*)d_in[1];
    // d_in[2] = encoder_lens: unused by the reference computation
    const float* Wk  = (const float*)d_in[3];
    // d_in[4] = bk: drops out (softmax shift invariance)
    const float* Wv  = (const float*)d_in[5];
    const float* bv  = (const float*)d_in[6];
    const float* Wq  = (const float*)d_in[7];
    const float* bq  = (const float*)d_in[8];

    float* out_ctx = (float*)d_out;              // [B, PP]
    float* attn    = out_ctx + BB * PP;          // [B, T]

    float* q    = (float*)d_ws;                  // B*PP
    float* qk   = q + BB * PP;                   // B*EH
    float* mc   = qk + BB * EH;                  // B*NC
    float* lc   = mc + BB * NC;                  // B*NC
    float* ctxc = lc + BB * NC;                  // B*NC*EH

    k_qproj<<<BB * 4, 256, 0, stream>>>(dec, Wq, bq, q);
    k_kfold<<<BB * 32, 256, 0, stream>>>(Wk, q, qk);
    attn_main<<<BB * NC, 256, 0, stream>>>(enc, qk, attn, mc, lc, ctxc);
    k_finish<<<BB * 4, 256, 0, stream>>>(mc, lc, ctxc, Wv, bv, out_ctx, attn);
}